// Round 5
// baseline (281.189 us; speedup 1.0000x reference)
//
#include <hip/hip_runtime.h>

// RoIBridge: gather sinusoidal positional embeddings per bbox coordinate,
// mask by obj_vec==1, write dense [B*T, 256] fp32 buffer.
// B=2048, T=128, D=64, IMAGE_SIZE=224 (table: 225x64 fp32 = 57.6 KB).
//
// Memory-bound: 268 MB output stream dominates (floor ~43 us @6.3 TB/s).
// R0 (ILP-1) kernel ~165 us; R3/R4 (ILP-4) ~64 us -> was latency-limited.
// R4 proved nt-vs-plain stores neutral. This round: ILP-8 (single variable)
// to test whether more independent load->gather->store chains close the
// remaining 1.5x gap to the write floor.
//  - wave (64 lanes) covers one 256-float row; 8 rows per wave.
//  - lanes 0-15 share one bbox coord (broadcast); each 16-lane group reads
//    one contiguous 256 B table row; stores fully coalesced 16 B/lane
//    (wave writes 8 KB contiguous total -> full lines, no RFO).

#define ROI_ROWS (2048 * 128)   // B*T = 262,144
#define ROI_IMG  224.0f
#define ROWS_PER_WAVE 8

typedef float vfloat4 __attribute__((ext_vector_type(4)));

__global__ __launch_bounds__(256) void RoIBridge_kernel(
    const float*   __restrict__ bboxs,   // [ROWS*4]
    const int*     __restrict__ objs,    // [ROWS]
    const vfloat4* __restrict__ table,   // [225*16] float4s
    vfloat4*       __restrict__ out)     // [ROWS*64] float4s
{
    const int tid  = blockIdx.x * 256 + threadIdx.x;
    const int wave = tid >> 6;
    const int lane = threadIdx.x & 63;
    const int c    = lane >> 4;        // coord 0..3 (16 lanes each)
    const int d4   = lane & 15;        // float4 within 64-float embedding

    const int row0 = wave * ROWS_PER_WAVE;

    // Phase 1: independent input loads up front (8 rows' obj + bbox)
    int   obj[ROWS_PER_WAVE];
    float frac[ROWS_PER_WAVE];
#pragma unroll
    for (int r = 0; r < ROWS_PER_WAVE; ++r) {
        obj[r]  = objs[row0 + r];
        frac[r] = bboxs[((row0 + r) << 2) + c];
    }

    // Phase 2: dependent gathers (8 independent chains in flight)
    vfloat4 e[ROWS_PER_WAVE];
#pragma unroll
    for (int r = 0; r < ROWS_PER_WAVE; ++r) {
        float v = fminf(fmaxf(frac[r] * ROI_IMG, 0.0f), ROI_IMG);
        const int idx = (int)v;            // trunc toward 0
        e[r] = table[idx * 16 + d4];       // 256B/row, coalesced
    }

    // Phase 3: masked stores (full-line, coalesced)
    const vfloat4 z = (vfloat4){0.0f, 0.0f, 0.0f, 0.0f};
#pragma unroll
    for (int r = 0; r < ROWS_PER_WAVE; ++r) {
        out[(row0 + r) * 64 + lane] = (obj[r] == 1) ? e[r] : z;
    }
}

extern "C" void kernel_launch(void* const* d_in, const int* in_sizes, int n_in,
                              void* d_out, int out_size, void* d_ws, size_t ws_size,
                              hipStream_t stream) {
    const float*   bboxs = (const float*)d_in[0];   // [2048,128,4] fp32
    const int*     objs  = (const int*)d_in[1];     // [2048,128] int32
    const vfloat4* table = (const vfloat4*)d_in[2]; // [225,64] fp32
    vfloat4* out = (vfloat4*)d_out;                 // [262144*64] float4

    // waves = ROWS/8 = 32,768 ; blocks (4 waves each) = 8,192
    RoIBridge_kernel<<<ROI_ROWS / (ROWS_PER_WAVE * 4), 256, 0, stream>>>(
        bboxs, objs, table, out);
}

// Round 7
// 262.645 us; speedup vs baseline: 1.0706x; 1.0706x over previous
//
#include <hip/hip_runtime.h>
#include <math.h>

// RoIBridge: positional-embedding expansion per bbox coordinate, masked by
// obj_vec==1, dense [B*T, 256] fp32 output.
// B=2048, T=128, D=64, IMAGE_SIZE=224.
//
// R7: same single-variable experiment as R6 (recompute sinusoidal embedding
// in-register instead of gathering the 57.6 KB table), but using standard
// sinf/cosf (OCML precise) instead of __sinf/__cosf native builtins — R6
// aborted at runtime with the native path (cause unclear: intrinsic issue vs
// infra flake). sinf/cosf cost ~20 VALU ops each; 67M of them ~ a few us
// chip-wide, hidden under the ~42 us 268 MB store stream.
//
// table[pos, i] = sin(pos * 10000^(-floor(i/2)/32)) even i, cos odd i.
// Angle abs err <= 224 * 1.2e-7 ~ 2.7e-5; sinf ~1 ulp -> total << 2e-2
// threshold.

#define ROI_ROWS (2048 * 128)   // B*T = 262,144
#define ROI_IMG  224.0f
#define ROWS_PER_WAVE 4         // ILP-4: best config from R3-R5 sweep

typedef float vfloat4 __attribute__((ext_vector_type(4)));

__global__ __launch_bounds__(256) void RoIBridge_kernel(
    const float* __restrict__ bboxs,   // [ROWS*4]
    const int*   __restrict__ objs,    // [ROWS]
    const float* __restrict__ table,   // unused (recomputed in-register)
    vfloat4*     __restrict__ out)     // [ROWS*64] float4s
{
    (void)table;
    const int tid  = blockIdx.x * 256 + threadIdx.x;
    const int wave = tid >> 6;
    const int lane = threadIdx.x & 63;
    const int c    = lane >> 4;        // coord 0..3 (16 lanes each)
    const int d4   = lane & 15;        // float4 within 64-float embedding

    // Per-thread frequency constants. Lane's 4 elements are i = d4*4 + j;
    // fi = i>>1 is {2*d4, 2*d4, 2*d4+1, 2*d4+1}.
    // scale = 10000^(-fi/32) = exp2(-fi * log2(10000)/32)
    const float L = 0.41524101186092029f;      // log2(10000)/32
    const float fi0 = (float)(d4 * 2);
    const float s0 = exp2f(-fi0 * L);          // for j=0 (sin), j=1 (cos)
    const float s1 = exp2f(-(fi0 + 1.0f) * L); // for j=2 (sin), j=3 (cos)

    const int row0 = wave * ROWS_PER_WAVE;

    // Phase 1: independent input loads up front
    int   obj[ROWS_PER_WAVE];
    float frac[ROWS_PER_WAVE];
#pragma unroll
    for (int r = 0; r < ROWS_PER_WAVE; ++r) {
        obj[r]  = objs[row0 + r];
        frac[r] = bboxs[((row0 + r) << 2) + c];
    }

    // Phase 2+3: compute embeddings in-register, masked coalesced stores
    const vfloat4 z = (vfloat4){0.0f, 0.0f, 0.0f, 0.0f};
#pragma unroll
    for (int r = 0; r < ROWS_PER_WAVE; ++r) {
        float v = fminf(fmaxf(frac[r] * ROI_IMG, 0.0f), ROI_IMG);
        const float pos = (float)(int)v;   // trunc toward 0, exact small int
        vfloat4 e;
        e.x = sinf(pos * s0);              // i even: sin
        e.y = cosf(pos * s0);              // i odd : cos (same freq)
        e.z = sinf(pos * s1);
        e.w = cosf(pos * s1);
        out[(row0 + r) * 64 + lane] = (obj[r] == 1) ? e : z;
    }
}

extern "C" void kernel_launch(void* const* d_in, const int* in_sizes, int n_in,
                              void* d_out, int out_size, void* d_ws, size_t ws_size,
                              hipStream_t stream) {
    const float* bboxs = (const float*)d_in[0];   // [2048,128,4] fp32
    const int*   objs  = (const int*)d_in[1];     // [2048,128] int32
    const float* table = (const float*)d_in[2];   // [225,64] fp32 (unused)
    vfloat4* out = (vfloat4*)d_out;               // [262144*64] float4

    // waves = ROWS/4 = 65,536 ; blocks (4 waves each) = 16,384
    RoIBridge_kernel<<<ROI_ROWS / (ROWS_PER_WAVE * 4), 256, 0, stream>>>(
        bboxs, objs, table, out);
}